// Round 4
// baseline (596.464 us; speedup 1.0000x reference)
//
#include <hip/hip_runtime.h>
#include <cstdint>
#include <cstddef>

#define KIN 300
#define KPAD 320
#define HIDDEN 128
#define BSZ 256
#define TSZ 512

typedef __attribute__((ext_vector_type(8))) short short8;
typedef __attribute__((ext_vector_type(4))) float f32x4;

__device__ __forceinline__ short f2bf(float f) {
  uint32_t u = __builtin_bit_cast(uint32_t, f);
  u = (u + 0x7FFFu + ((u >> 16) & 1u)) >> 16;
  return (short)u;
}
__device__ __forceinline__ float bf2f(short s) {
  uint32_t u = ((uint32_t)(uint16_t)s) << 16;
  return __builtin_bit_cast(float, u);
}
__device__ __forceinline__ float bflo(uint32_t u) {
  return __builtin_bit_cast(float, u << 16);
}
__device__ __forceinline__ float bfhi(uint32_t u) {
  return __builtin_bit_cast(float, u & 0xFFFF0000u);
}
__device__ __forceinline__ uint32_t pack2bf(float a, float b) {
  return (uint32_t)(uint16_t)f2bf(a) | ((uint32_t)(uint16_t)f2bf(b) << 16);
}
__device__ __forceinline__ float tanhf_fast(float v) {
  const float e = __expf(-2.0f * fabsf(v));
  const float r = __fdividef(1.0f - e, 1.0f + e);
  return copysignf(r, v);
}
// Barrier that waits LDS ops but leaves global loads (vmcnt) in flight.
__device__ __forceinline__ void barrier_lds() {
  asm volatile("s_waitcnt lgkmcnt(0)\n\ts_barrier" ::: "memory");
}

// ---------------- Phase 0: W_ih -> bf16, K zero-padded to 320 --------------
__global__ __launch_bounds__(256) void wcvt_bf16(const float* __restrict__ W,
                                                 short* __restrict__ W16) {
  const int i = blockIdx.x * 256 + threadIdx.x;  // over 128*320
  if (i >= HIDDEN * KPAD) return;
  const int n = i / KPAD, k = i % KPAD;
  W16[i] = (k < KIN) ? f2bf(W[n * KIN + k]) : (short)0;
}

// ---------------- Phase 1: xp = x @ W_ih^T + (b_ih+b_hh), bf16 [T][B][H] ---
// No LDS, no barriers. Wave w owns rows [m0b+32w, m0b+32w+32) (2 m-tiles),
// all 8 n-tiles. A-frags direct from global fp32 (x read exactly once,
// 64-B segments), B-frags are ready short8 loads from pre-converted W16
// (L2/L3-resident). 2-chunk-deep register pipeline; K-tail: clamped A
// addresses x zero-padded B columns.
__global__ __launch_bounds__(256) void xp_gemm_direct(
    const float* __restrict__ x, const short* __restrict__ W16,
    const float* __restrict__ b_ih, const float* __restrict__ b_hh,
    short* __restrict__ xp16) {
  const int tid = threadIdx.x;
  const int lane = tid & 63, w = tid >> 6;
  const int q = lane >> 4, c = lane & 15;
  const int m0b = blockIdx.x * 128;
  const int mrow0 = m0b + w * 32;

  const float* arow0 = x + (size_t)(mrow0 + c) * KIN;
  const float* arow1 = x + (size_t)(mrow0 + 16 + c) * KIN;
  const short* bp = W16 + (size_t)c * KPAD + q * 8;  // + nt*16*KPAD + kc*32

  f32x4 acc[2][8];
#pragma unroll
  for (int mt = 0; mt < 2; ++mt)
#pragma unroll
    for (int nt = 0; nt < 8; ++nt) acc[mt][nt] = (f32x4){0.f, 0.f, 0.f, 0.f};

  float4 a0[2][2], a1[2][2];
  short8 bq0[8], bq1[8];

#define LOADA(DST, KC)                                                  \
  {                                                                     \
    const int kb = (KC)*32 + q * 8;                                     \
    const int o1 = (kb + 3 < KIN) ? kb : 292;                           \
    const int o2 = (kb + 7 < KIN) ? kb + 4 : 292;                       \
    DST[0][0] = *(const float4*)(arow0 + o1);                           \
    DST[0][1] = *(const float4*)(arow0 + o2);                           \
    DST[1][0] = *(const float4*)(arow1 + o1);                           \
    DST[1][1] = *(const float4*)(arow1 + o2);                           \
  }
#define LOADB(DST, KC)                                                  \
  {                                                                     \
    _Pragma("unroll") for (int nt = 0; nt < 8; ++nt)                    \
        DST[nt] = *(const short8*)(bp + nt * 16 * KPAD + (KC)*32);      \
  }
#define COMPUTE(A, BQ)                                                  \
  {                                                                     \
    _Pragma("unroll") for (int mt = 0; mt < 2; ++mt) {                  \
      short8 af;                                                        \
      const float4 u = A[mt][0], v = A[mt][1];                          \
      const uint32_t p0 = pack2bf(u.x, u.y), p1 = pack2bf(u.z, u.w);    \
      const uint32_t p2 = pack2bf(v.x, v.y), p3 = pack2bf(v.z, v.w);    \
      af[0] = (short)p0; af[1] = (short)(p0 >> 16);                     \
      af[2] = (short)p1; af[3] = (short)(p1 >> 16);                     \
      af[4] = (short)p2; af[5] = (short)(p2 >> 16);                     \
      af[6] = (short)p3; af[7] = (short)(p3 >> 16);                     \
      _Pragma("unroll") for (int nt = 0; nt < 8; ++nt)                  \
          acc[mt][nt] = __builtin_amdgcn_mfma_f32_16x16x32_bf16(        \
              af, BQ[nt], acc[mt][nt], 0, 0, 0);                        \
    }                                                                   \
  }

  LOADA(a0, 0) LOADB(bq0, 0)
  LOADA(a1, 1) LOADB(bq1, 1)
#pragma unroll
  for (int kc = 0; kc < 10; ++kc) {
    if ((kc & 1) == 0) {
      COMPUTE(a0, bq0)
      if (kc + 2 < 10) { LOADA(a0, kc + 2) LOADB(bq0, kc + 2) }
    } else {
      COMPUTE(a1, bq1)
      if (kc + 2 < 10) { LOADA(a1, kc + 2) LOADB(bq1, kc + 2) }
    }
  }
#undef LOADA
#undef LOADB
#undef COMPUTE

  // epilogue: bias + store bf16 to xp16[t][b][h];  b = m>>9, t = m&511
  float bias[8];
#pragma unroll
  for (int nt = 0; nt < 8; ++nt) {
    const int n = nt * 16 + c;
    bias[nt] = b_ih[n] + b_hh[n];
  }
  const int bidx = m0b >> 9;
  const int t0 = (m0b & 511) + w * 32;
#pragma unroll
  for (int mt = 0; mt < 2; ++mt) {
#pragma unroll
    for (int r = 0; r < 4; ++r) {
      const int t = t0 + mt * 16 + q * 4 + r;
      short* orow = xp16 + ((size_t)t * BSZ + bidx) * HIDDEN;
#pragma unroll
      for (int nt = 0; nt < 8; ++nt)
        orow[nt * 16 + c] = f2bf(acc[mt][nt][r] + bias[nt]);
    }
  }
}

// ---------------- Phase 2: MFMA-batched scan + fused FC --------------------
// 16 blocks x 16 batch rows. xp (bf16, [T][B][H]) prefetched in 8-step
// chunks into two alternating register banks (16 dwordx2 per chunk, issued
// a full chunk ahead -> per-register vmcnt waits are satisfied). Per-step
// path: ds_read ht -> 8 MFMA (2+2 split) -> tanh -> ds_write -> barrier.
__global__ __launch_bounds__(256, 1) void rnn_scan_reg(
    const short* __restrict__ xp16, const float* __restrict__ Whh,
    const float* __restrict__ fc_w, const float* __restrict__ fc_b,
    float* __restrict__ out) {
  __shared__ __align__(16) short ht[2][16][136];
  const int tid = threadIdx.x;
  const int lane = tid & 63, w = tid >> 6;
  const int q = lane >> 4, c = lane & 15;
  const int b0 = blockIdx.x * 16;

  // W_hh A-frags: wave w owns hidden-out rows [32w, 32w+32)
  short8 aw[2][4];
#pragma unroll
  for (int ti = 0; ti < 2; ++ti)
#pragma unroll
    for (int kc = 0; kc < 4; ++kc) {
      const float* src =
          Whh + (size_t)(w * 32 + ti * 16 + c) * HIDDEN + kc * 32 + q * 8;
      const float4 v0 = *(const float4*)(src);
      const float4 v1 = *(const float4*)(src + 4);
      short8 t;
      t[0] = f2bf(v0.x); t[1] = f2bf(v0.y); t[2] = f2bf(v0.z); t[3] = f2bf(v0.w);
      t[4] = f2bf(v1.x); t[5] = f2bf(v1.y); t[6] = f2bf(v1.z); t[7] = f2bf(v1.w);
      aw[ti][kc] = t;
    }

  // h0 = 0
  {
    uint32_t* z = (uint32_t*)&ht[0][0][0];
    for (int i = tid; i < 1088; i += 256) z[i] = 0;
  }

  const int hb0 = w * 32 + q * 4;
  const int hb1 = hb0 + 16;
  // lane base into xp16: [t][b0+c][hb0]; t-stride = 32768 shorts
  const short* xl = xp16 + (size_t)(b0 + c) * HIDDEN + hb0;

  uint2 xa[8][2], xb[8][2];
  // prologue: chunk 0 -> xa
#pragma unroll
  for (int s = 0; s < 8; ++s) {
    const short* p = xl + (size_t)s * (BSZ * HIDDEN);
    xa[s][0] = *(const uint2*)(p);
    xa[s][1] = *(const uint2*)(p + 16);
  }
  __syncthreads();

  const f32x4 zero4 = {0.f, 0.f, 0.f, 0.f};

#define CHUNK_BODY(USE, LDB, C0, DOLOAD)                                       \
  {                                                                            \
    if (DOLOAD) {                                                              \
      const short* pn = xl + (size_t)((C0) + 1) * 8 * (BSZ * HIDDEN);          \
      _Pragma("unroll") for (int s = 0; s < 8; ++s) {                          \
        const short* p = pn + (size_t)s * (BSZ * HIDDEN);                      \
        LDB[s][0] = *(const uint2*)(p);                                        \
        LDB[s][1] = *(const uint2*)(p + 16);                                   \
      }                                                                        \
    }                                                                          \
    _Pragma("unroll") for (int s = 0; s < 8; ++s) {                            \
      const int rb = s & 1;                                                    \
      const short8 bh0 = *(const short8*)&ht[rb][c][0 + q * 8];                \
      const short8 bh1 = *(const short8*)&ht[rb][c][32 + q * 8];               \
      const short8 bh2 = *(const short8*)&ht[rb][c][64 + q * 8];               \
      const short8 bh3 = *(const short8*)&ht[rb][c][96 + q * 8];               \
      const uint2 u0 = USE[s][0], u1 = USE[s][1];                              \
      f32x4 p0 = {bflo(u0.x), bfhi(u0.x), bflo(u0.y), bfhi(u0.y)};             \
      f32x4 p1 = {bflo(u1.x), bfhi(u1.x), bflo(u1.y), bfhi(u1.y)};             \
      f32x4 q0 = zero4, q1 = zero4;                                            \
      p0 = __builtin_amdgcn_mfma_f32_16x16x32_bf16(aw[0][0], bh0, p0, 0, 0, 0);\
      p1 = __builtin_amdgcn_mfma_f32_16x16x32_bf16(aw[1][0], bh0, p1, 0, 0, 0);\
      q0 = __builtin_amdgcn_mfma_f32_16x16x32_bf16(aw[0][1], bh1, q0, 0, 0, 0);\
      q1 = __builtin_amdgcn_mfma_f32_16x16x32_bf16(aw[1][1], bh1, q1, 0, 0, 0);\
      p0 = __builtin_amdgcn_mfma_f32_16x16x32_bf16(aw[0][2], bh2, p0, 0, 0, 0);\
      p1 = __builtin_amdgcn_mfma_f32_16x16x32_bf16(aw[1][2], bh2, p1, 0, 0, 0);\
      q0 = __builtin_amdgcn_mfma_f32_16x16x32_bf16(aw[0][3], bh3, q0, 0, 0, 0);\
      q1 = __builtin_amdgcn_mfma_f32_16x16x32_bf16(aw[1][3], bh3, q1, 0, 0, 0);\
      const f32x4 s0 = p0 + q0;                                                \
      const f32x4 s1 = p1 + q1;                                                \
      uint2 w0, w1;                                                            \
      w0.x = pack2bf(tanhf_fast(s0[0]), tanhf_fast(s0[1]));                    \
      w0.y = pack2bf(tanhf_fast(s0[2]), tanhf_fast(s0[3]));                    \
      w1.x = pack2bf(tanhf_fast(s1[0]), tanhf_fast(s1[1]));                    \
      w1.y = pack2bf(tanhf_fast(s1[2]), tanhf_fast(s1[3]));                    \
      *(uint2*)&ht[rb ^ 1][c][hb0] = w0;                                       \
      *(uint2*)&ht[rb ^ 1][c][hb1] = w1;                                       \
      barrier_lds();                                                           \
    }                                                                          \
  }

  for (int cc = 0; cc < 32; ++cc) {
    const int c0 = cc * 2;
    CHUNK_BODY(xa, xb, c0, true)        // use chunk c0, load c0+1 -> xb
    CHUNK_BODY(xb, xa, c0 + 1, cc < 31) // use chunk c0+1, load c0+2 -> xa
  }
#undef CHUNK_BODY

  // h_last in ht[0] (t=511 wrote rb^1 = 0). FC: 32 outputs/block.
  if (tid < 32) {
    const int bi = tid >> 1, cls = tid & 1;
    float s = fc_b[cls];
    const float* fw = fc_w + cls * HIDDEN;
#pragma unroll 8
    for (int k = 0; k < HIDDEN; k += 4) {
      s = fmaf(bf2f(ht[0][bi][k + 0]), fw[k + 0], s);
      s = fmaf(bf2f(ht[0][bi][k + 1]), fw[k + 1], s);
      s = fmaf(bf2f(ht[0][bi][k + 2]), fw[k + 2], s);
      s = fmaf(bf2f(ht[0][bi][k + 3]), fw[k + 3], s);
    }
    out[(b0 + bi) * 2 + cls] = s;
  }
}

extern "C" void kernel_launch(void* const* d_in, const int* in_sizes, int n_in,
                              void* d_out, int out_size, void* d_ws, size_t ws_size,
                              hipStream_t stream) {
  const float* x    = (const float*)d_in[0];
  const float* W_ih = (const float*)d_in[1];
  const float* W_hh = (const float*)d_in[2];
  const float* b_ih = (const float*)d_in[3];
  const float* b_hh = (const float*)d_in[4];
  const float* fc_w = (const float*)d_in[5];
  const float* fc_b = (const float*)d_in[6];
  short* xp16 = (short*)d_ws;                            // 32 MiB bf16 [T][B][H]
  short* W16  = (short*)((char*)d_ws + (33u << 20));     // 80 KB bf16 [128][320]
  float* out  = (float*)d_out;

  wcvt_bf16<<<(HIDDEN * KPAD + 255) / 256, 256, 0, stream>>>(W_ih, W16);
  xp_gemm_direct<<<(BSZ * TSZ) / 128, 256, 0, stream>>>(x, W16, b_ih, b_hh, xp16);
  rnn_scan_reg<<<BSZ / 16, 256, 0, stream>>>(xp16, W_hh, fc_w, fc_b, out);
}

// Round 5
// 509.649 us; speedup vs baseline: 1.1703x; 1.1703x over previous
//
#include <hip/hip_runtime.h>
#include <cstdint>
#include <cstddef>

#define KIN 300
#define KPAD 320
#define HIDDEN 128
#define BSZ 256
#define TSZ 512

typedef __attribute__((ext_vector_type(8))) short short8;
typedef __attribute__((ext_vector_type(4))) float f32x4;

__device__ __forceinline__ short f2bf(float f) {
  uint32_t u = __builtin_bit_cast(uint32_t, f);
  u = (u + 0x7FFFu + ((u >> 16) & 1u)) >> 16;
  return (short)u;
}
__device__ __forceinline__ float bf2f(short s) {
  uint32_t u = ((uint32_t)(uint16_t)s) << 16;
  return __builtin_bit_cast(float, u);
}
__device__ __forceinline__ float bflo(uint32_t u) {
  return __builtin_bit_cast(float, u << 16);
}
__device__ __forceinline__ float bfhi(uint32_t u) {
  return __builtin_bit_cast(float, u & 0xFFFF0000u);
}
__device__ __forceinline__ uint32_t pack2bf(float a, float b) {
  return (uint32_t)(uint16_t)f2bf(a) | ((uint32_t)(uint16_t)f2bf(b) << 16);
}
// tanh(x) = 1 - 2/(exp2(x*2*log2e)+1); exact at +/-1 extremes, 5 VALU inst.
__device__ __forceinline__ float tanhf_fast(float v) {
  const float e = __builtin_amdgcn_exp2f(v * 2.88539008177793f);
  return fmaf(-2.0f, __builtin_amdgcn_rcpf(e + 1.0f), 1.0f);
}
// Barrier that waits LDS ops but leaves global/DMA (vmcnt) in flight.
__device__ __forceinline__ void barrier_lds() {
  asm volatile("s_waitcnt lgkmcnt(0)\n\ts_barrier" ::: "memory");
}
__device__ __forceinline__ void barrier_all() {
  asm volatile("s_waitcnt vmcnt(0) lgkmcnt(0)\n\ts_barrier" ::: "memory");
}
// async 16B/lane global->LDS DMA: lds dst = uniform base + lane*16
__device__ __forceinline__ void dma16(const short* g, short* l) {
  __builtin_amdgcn_global_load_lds(
      (const __attribute__((address_space(1))) void*)g,
      (__attribute__((address_space(3))) void*)l, 16, 0, 0);
}

// ---------------- Phase 0: W_ih -> bf16, K zero-padded to 320 --------------
__global__ __launch_bounds__(256) void wcvt_bf16(const float* __restrict__ W,
                                                 short* __restrict__ W16) {
  const int i = blockIdx.x * 256 + threadIdx.x;
  if (i >= HIDDEN * KPAD) return;
  const int n = i / KPAD, k = i % KPAD;
  W16[i] = (k < KIN) ? f2bf(W[n * KIN + k]) : (short)0;
}

// ---------------- Phase 1: xp = x @ W_ih^T + bias, DMA-native layout -------
// Block = 16 batches x 4 timesteps = 64 rows; x row-tile staged in LDS ONCE
// (bf16, 42 KB) -> x read exactly 1x from HBM. MFMA roles: A = W_ih (M=h),
// B = x rows (N); C regs are h-minor -> epilogue emits xp16 in the scan's
// DMA layout [t][bg][g=h/4][b16][r=h%4] via LDS transpose + coalesced copy.
__global__ __launch_bounds__(256) void xp_gemm_mfma(
    const float* __restrict__ x, const short* __restrict__ W16,
    const float* __restrict__ b_ih, const float* __restrict__ b_hh,
    short* __restrict__ xp16) {
  __shared__ __align__(16) short As[64 * 328];  // 42 KB; reused as epilogue stage
  const int tid = threadIdx.x;
  const int lane = tid & 63, w = tid >> 6;
  const int q = lane >> 4, c = lane & 15;
  const int bg = blockIdx.x & 15, tc = blockIdx.x >> 4;
  const int b0 = bg * 16, t0 = tc * 4;

  // ---- stage x tile (64 rows x 300 K) as bf16, padded stride 328 ----
#pragma unroll
  for (int i = 0; i < 19; ++i) {
    const int f = tid + 256 * i;  // float4 index over 64*75
    if (f < 4800) {
      const int rr = f / 75;
      const int k4 = f - rr * 75;
      const int b_in = rr >> 2, t_loc = rr & 3;
      const float4 v = *(const float4*)(
          x + ((size_t)(b0 + b_in) * TSZ + t0 + t_loc) * KIN + k4 * 4);
      uint2 pv;
      pv.x = pack2bf(v.x, v.y);
      pv.y = pack2bf(v.z, v.w);
      *(uint2*)&As[rr * 328 + k4 * 4] = pv;
    }
  }
  if (tid < 64) {  // zero-pad k = 300..319
    const uint2 z = {0u, 0u};
#pragma unroll
    for (int j = 0; j < 5; ++j) *(uint2*)&As[tid * 328 + 300 + j * 4] = z;
  }
  __syncthreads();

  // wave w owns h-tiles {2w, 2w+1} x all 4 row-tiles
  f32x4 acc[2][4];
#pragma unroll
  for (int ht = 0; ht < 2; ++ht)
#pragma unroll
    for (int rt = 0; rt < 4; ++rt) acc[ht][rt] = (f32x4){0.f, 0.f, 0.f, 0.f};

  // A-frags (W16, L2-resident): lane (q,c) -> A[m=c][k=q*8+j]
  const short* wp0 = W16 + (size_t)((2 * w + 0) * 16 + c) * KPAD + q * 8;
  const short* wp1 = W16 + (size_t)((2 * w + 1) * 16 + c) * KPAD + q * 8;
  short8 af[2][2];
  af[0][0] = *(const short8*)(wp0);
  af[0][1] = *(const short8*)(wp1);
#pragma unroll
  for (int kc = 0; kc < 10; ++kc) {
    const int cur = kc & 1;
    if (kc < 9) {
      af[cur ^ 1][0] = *(const short8*)(wp0 + (kc + 1) * 32);
      af[cur ^ 1][1] = *(const short8*)(wp1 + (kc + 1) * 32);
    }
    short8 bq[4];
#pragma unroll
    for (int rt = 0; rt < 4; ++rt)
      bq[rt] = *(const short8*)&As[(rt * 16 + c) * 328 + kc * 32 + q * 8];
#pragma unroll
    for (int ht = 0; ht < 2; ++ht)
#pragma unroll
      for (int rt = 0; rt < 4; ++rt)
        acc[ht][rt] = __builtin_amdgcn_mfma_f32_16x16x32_bf16(
            af[cur][ht], bq[rt], acc[ht][rt], 0, 0, 0);
  }
  __syncthreads();  // all B-frag reads done; As becomes the stage buffer

  // ---- epilogue: bias, pack, LDS transpose to [t][g][b] (padded) ----
  float4 bsum[2];
#pragma unroll
  for (int ht = 0; ht < 2; ++ht) {
    const int h0 = (2 * w + ht) * 16 + q * 4;
    const float4 bi = *(const float4*)(b_ih + h0);
    const float4 bh = *(const float4*)(b_hh + h0);
    bsum[ht] = make_float4(bi.x + bh.x, bi.y + bh.y, bi.z + bh.z, bi.w + bh.w);
  }
  // stage layout: t stride 2312, g stride 72, b_in stride 4 (shorts)
#pragma unroll
  for (int ht = 0; ht < 2; ++ht) {
    const int g = (2 * w + ht) * 4 + q;
#pragma unroll
    for (int rt = 0; rt < 4; ++rt) {
      const int b_in = rt * 4 + (c >> 2);
      const int t_loc = c & 3;
      uint2 pv;
      pv.x = pack2bf(acc[ht][rt][0] + bsum[ht].x, acc[ht][rt][1] + bsum[ht].y);
      pv.y = pack2bf(acc[ht][rt][2] + bsum[ht].z, acc[ht][rt][3] + bsum[ht].w);
      *(uint2*)&As[t_loc * 2312 + g * 72 + b_in * 4] = pv;
    }
  }
  __syncthreads();
  // ---- coalesced copy-out: per t_loc a dense 4 KB region ----
#pragma unroll
  for (int i = 0; i < 4; ++i) {
    const int4 vv =
        *(const int4*)&As[i * 2312 + (tid >> 3) * 72 + (tid & 7) * 8];
    *(int4*)(xp16 + ((size_t)(t0 + i) * 16 + bg) * 2048 + tid * 8) = vv;
  }
}

// ---------------- Phase 2: MFMA-batched scan + fused FC --------------------
// 16 blocks x 16 batch rows. xp chunks (8 steps = 32 KB) DMA'd into
// double-buffered LDS via global_load_lds, issued one full chunk (~2400 cyc)
// ahead; per-step barriers wait lgkmcnt only, chunk boundary waits vmcnt(0).
__global__ __launch_bounds__(256, 1) void rnn_scan_dma(
    const short* __restrict__ xp16, const float* __restrict__ Whh,
    const float* __restrict__ fc_w, const float* __restrict__ fc_b,
    float* __restrict__ out) {
  __shared__ __align__(16) short xs[2][8][2048];  // 64 KB
  __shared__ __align__(16) short ht[2][16][136];  // 8.5 KB
  const int tid = threadIdx.x;
  const int lane = tid & 63, w = tid >> 6;
  const int q = lane >> 4, c = lane & 15;
  const int bg = blockIdx.x;

  // W_hh A-frags: wave w owns h-out rows [32w, 32w+32)
  short8 aw[2][4];
#pragma unroll
  for (int ti = 0; ti < 2; ++ti)
#pragma unroll
    for (int kc = 0; kc < 4; ++kc) {
      const float* src =
          Whh + (size_t)(w * 32 + ti * 16 + c) * HIDDEN + kc * 32 + q * 8;
      const float4 v0 = *(const float4*)(src);
      const float4 v1 = *(const float4*)(src + 4);
      short8 t;
      t[0] = f2bf(v0.x); t[1] = f2bf(v0.y); t[2] = f2bf(v0.z); t[3] = f2bf(v0.w);
      t[4] = f2bf(v1.x); t[5] = f2bf(v1.y); t[6] = f2bf(v1.z); t[7] = f2bf(v1.w);
      aw[ti][kc] = t;
    }

  // h0 = 0
  {
    uint32_t* z = (uint32_t*)&ht[0][0][0];
    for (int i = tid; i < 1088; i += 256) z[i] = 0;
  }

  // DMA issue: wave w covers chunk-steps {2w, 2w+1}, 4 x 1KB insts each
#define ISSUE_CHUNK(CH, BUF)                                                  \
  {                                                                           \
    _Pragma("unroll") for (int sr = 0; sr < 2; ++sr) {                        \
      const int s = 2 * w + sr;                                               \
      const short* srcb =                                                     \
          xp16 + ((size_t)((CH)*8 + s) * 16 + bg) * 2048 + lane * 8;          \
      _Pragma("unroll") for (int j = 0; j < 4; ++j)                           \
          dma16(srcb + j * 512, &xs[BUF][s][j * 512]);                        \
    }                                                                         \
  }

  ISSUE_CHUNK(0, 0)
  barrier_all();  // chunk-0 DMA landed; ht zero + everyone ready

  const int g0 = w * 8 + q, g1 = w * 8 + 4 + q;
  const int hb0 = w * 32 + q * 4, hb1 = hb0 + 16;
  const f32x4 zero4 = {0.f, 0.f, 0.f, 0.f};

  for (int cc = 0; cc < 64; ++cc) {
    const int buf = cc & 1;
    if (cc + 1 < 64) ISSUE_CHUNK(cc + 1, buf ^ 1)
#pragma unroll
    for (int s = 0; s < 8; ++s) {
      const int rb = s & 1;  // global t = cc*8+s; cc even so parity = s&1
      const short8 bh0 = *(const short8*)&ht[rb][c][0 + q * 8];
      const short8 bh1 = *(const short8*)&ht[rb][c][32 + q * 8];
      const short8 bh2 = *(const short8*)&ht[rb][c][64 + q * 8];
      const short8 bh3 = *(const short8*)&ht[rb][c][96 + q * 8];
      const uint2 u0 = *(const uint2*)&xs[buf][s][g0 * 64 + c * 4];
      const uint2 u1 = *(const uint2*)&xs[buf][s][g1 * 64 + c * 4];
      f32x4 p0 = {bflo(u0.x), bfhi(u0.x), bflo(u0.y), bfhi(u0.y)};
      f32x4 p1 = {bflo(u1.x), bfhi(u1.x), bflo(u1.y), bfhi(u1.y)};
      f32x4 q0 = zero4, q1 = zero4;
      p0 = __builtin_amdgcn_mfma_f32_16x16x32_bf16(aw[0][0], bh0, p0, 0, 0, 0);
      p1 = __builtin_amdgcn_mfma_f32_16x16x32_bf16(aw[1][0], bh0, p1, 0, 0, 0);
      q0 = __builtin_amdgcn_mfma_f32_16x16x32_bf16(aw[0][1], bh1, q0, 0, 0, 0);
      q1 = __builtin_amdgcn_mfma_f32_16x16x32_bf16(aw[1][1], bh1, q1, 0, 0, 0);
      p0 = __builtin_amdgcn_mfma_f32_16x16x32_bf16(aw[0][2], bh2, p0, 0, 0, 0);
      p1 = __builtin_amdgcn_mfma_f32_16x16x32_bf16(aw[1][2], bh2, p1, 0, 0, 0);
      q0 = __builtin_amdgcn_mfma_f32_16x16x32_bf16(aw[0][3], bh3, q0, 0, 0, 0);
      q1 = __builtin_amdgcn_mfma_f32_16x16x32_bf16(aw[1][3], bh3, q1, 0, 0, 0);
      const f32x4 s0 = p0 + q0;
      const f32x4 s1 = p1 + q1;
      uint2 w0, w1;
      w0.x = pack2bf(tanhf_fast(s0[0]), tanhf_fast(s0[1]));
      w0.y = pack2bf(tanhf_fast(s0[2]), tanhf_fast(s0[3]));
      w1.x = pack2bf(tanhf_fast(s1[0]), tanhf_fast(s1[1]));
      w1.y = pack2bf(tanhf_fast(s1[2]), tanhf_fast(s1[3]));
      *(uint2*)&ht[rb ^ 1][c][hb0] = w0;
      *(uint2*)&ht[rb ^ 1][c][hb1] = w1;
      barrier_lds();
    }
    barrier_all();  // next chunk's DMA (issued ~8 steps ago) must be landed
  }
#undef ISSUE_CHUNK

  // h_last in ht[0] (t=511 wrote rb^1 = 0). FC: 32 outputs/block.
  if (tid < 32) {
    const int bi = tid >> 1, cls = tid & 1;
    float s = fc_b[cls];
    const float* fw = fc_w + cls * HIDDEN;
#pragma unroll 8
    for (int k = 0; k < HIDDEN; k += 4) {
      s = fmaf(bf2f(ht[0][bi][k + 0]), fw[k + 0], s);
      s = fmaf(bf2f(ht[0][bi][k + 1]), fw[k + 1], s);
      s = fmaf(bf2f(ht[0][bi][k + 2]), fw[k + 2], s);
      s = fmaf(bf2f(ht[0][bi][k + 3]), fw[k + 3], s);
    }
    out[(bg * 16 + bi) * 2 + cls] = s;
  }
}

extern "C" void kernel_launch(void* const* d_in, const int* in_sizes, int n_in,
                              void* d_out, int out_size, void* d_ws, size_t ws_size,
                              hipStream_t stream) {
  const float* x    = (const float*)d_in[0];
  const float* W_ih = (const float*)d_in[1];
  const float* W_hh = (const float*)d_in[2];
  const float* b_ih = (const float*)d_in[3];
  const float* b_hh = (const float*)d_in[4];
  const float* fc_w = (const float*)d_in[5];
  const float* fc_b = (const float*)d_in[6];
  short* xp16 = (short*)d_ws;                         // 32 MiB bf16 [T][16bg][2048]
  short* W16  = (short*)((char*)d_ws + (33u << 20));  // 80 KB bf16 [128][320]
  float* out  = (float*)d_out;

  wcvt_bf16<<<(HIDDEN * KPAD + 255) / 256, 256, 0, stream>>>(W_ih, W16);
  xp_gemm_mfma<<<16 * (TSZ / 4), 256, 0, stream>>>(x, W16, b_ih, b_hh, xp16);
  rnn_scan_dma<<<16, 256, 0, stream>>>(xp16, W_hh, fc_w, fc_b, out);
}